// Round 5
// baseline (452.962 us; speedup 1.0000x reference)
//
#include <hip/hip_runtime.h>

// GaborAutoencoder on MI355X (gfx950)
// split fp32 -> fp16 (hi, lo*4096) -> 3-pass split-precision MFMA GEMMs -> Gabor synth.
// R10: G1 restructured around the LDS-unit bottleneck (R9 accounting: MFMA 1862cy,
//      LDS 1700cy per K-step, alternating not overlapping -> 4500cy steps).
//      B operand now loaded DIRECT global->VGPR (per-lane dwordx4 matches the
//      16x16x32 B-frag layout exactly); wave grid 1x4 (wave = all 128 rows x 64 cols)
//      so each B byte is fetched once per block. LDS holds only A: 48KB/step ~ 580cy,
//      off the critical path. B loads issued BEFORE A-staging so compiler B-wait is
//      vmcnt(4), A prefetch stays in flight. A staging swizzle + frag-read swizzle
//      (R4-verified) unchanged. G2-4 + synth + splits + combine1: R9/R5-exact.

#define SIGNAL_LEN 2048
#define NWAV 32

typedef _Float16 f16x8 __attribute__((ext_vector_type(8)));
typedef _Float16 f16x4 __attribute__((ext_vector_type(4)));
typedef float    f32x4 __attribute__((ext_vector_type(4)));

__device__ __forceinline__ void load16_lds(const _Float16* g, _Float16* l) {
  __builtin_amdgcn_global_load_lds((const __attribute__((address_space(1))) void*)g,
                                   (__attribute__((address_space(3))) void*)l,
                                   16, 0, 0);
}

struct HL { _Float16 h, l; };
__device__ __forceinline__ HL split_one(float a) {
  HL r;
  r.h = (_Float16)a;
  r.l = (_Float16)((a - (float)r.h) * 4096.0f);
  return r;
}

// ---------------------------------------------------------------------------
// X split: fp32 float4 -> hi/lo f16x4
// ---------------------------------------------------------------------------
__global__ void split_x(const float4* __restrict__ src, f16x4* __restrict__ dh,
                        f16x4* __restrict__ dl) {
  int i = blockIdx.x * 256 + threadIdx.x;  // 4194304 float4s
  float4 v = src[i];
  float a[4] = {v.x, v.y, v.z, v.w};
  f16x4 h, l;
#pragma unroll
  for (int j = 0; j < 4; j++) {
    HL r = split_one(a[j]);
    h[j] = r.h;
    l[j] = r.l;
  }
  dh[i] = h;
  dl[i] = l;
}

// ---------------------------------------------------------------------------
// all weight splits in one launch (scaled x256); W4 padded 160x256 -> 256x256
// ---------------------------------------------------------------------------
__global__ void split_weights(const float* __restrict__ W1, const float* __restrict__ W2,
                              const float* __restrict__ W3, const float* __restrict__ W4,
                              const float* __restrict__ b4,
                              f16x4* __restrict__ W1h, f16x4* __restrict__ W1l,
                              f16x4* __restrict__ W2h, f16x4* __restrict__ W2l,
                              f16x4* __restrict__ W3h, f16x4* __restrict__ W3l,
                              f16x4* __restrict__ W4h, f16x4* __restrict__ W4l,
                              float* __restrict__ b4p) {
  const int blk = blockIdx.x;
  const int tid = threadIdx.x;
  if (blk < 4736) {
    const float4* src;
    f16x4 *dh, *dl;
    int i;
    if (blk < 4096) {
      src = (const float4*)W1; dh = W1h; dl = W1l; i = blk * 256 + tid;
    } else if (blk < 4608) {
      src = (const float4*)W2; dh = W2h; dl = W2l; i = (blk - 4096) * 256 + tid;
    } else {
      src = (const float4*)W3; dh = W3h; dl = W3l; i = (blk - 4608) * 256 + tid;
    }
    float4 v = src[i];
    float a[4] = {v.x * 256.0f, v.y * 256.0f, v.z * 256.0f, v.w * 256.0f};
    f16x4 h, l;
#pragma unroll
    for (int j = 0; j < 4; j++) {
      HL r = split_one(a[j]);
      h[j] = r.h;
      l[j] = r.l;
    }
    dh[i] = h;
    dl[i] = l;
  } else if (blk < 4800) {
    int i = (blk - 4736) * 256 + tid;
    int i4 = i << 2;
    int row = i4 >> 8;
    f16x4 h, l;
#pragma unroll
    for (int j = 0; j < 4; j++) {
      float a = (row < 160) ? W4[i4 + j] * 256.0f : 0.0f;
      HL r = split_one(a);
      h[j] = r.h;
      l[j] = r.l;
    }
    W4h[i] = h;
    W4l[i] = l;
  } else {
    b4p[tid] = (tid < 160) ? b4[tid] : 0.0f;
  }
}

// ---------------------------------------------------------------------------
// R5 fused GEMM (G2-4): fp16x2 split-precision, double-buffered, fused epilogue.
// C[M,N] = A[M,K]*B[N,K]^T (+bias, relu). Tile TM x TN, 256 threads = 4 waves
// (2x2), wave tile (TM/2)x(TN/2) of 16x16x32 MFMAs. One barrier per K32 step.
// ---------------------------------------------------------------------------
template <int TM, int TN, int N, int K, bool RELU, bool SPLIT_OUT>
__global__ void __launch_bounds__(256, 2)
gemm_fused(const _Float16* __restrict__ Ah, const _Float16* __restrict__ Al,
           const _Float16* __restrict__ Bh, const _Float16* __restrict__ Bl,
           const float* __restrict__ bias,
           _Float16* __restrict__ Ch, _Float16* __restrict__ Cl,
           float* __restrict__ Cf) {
  constexpr int AM = TM / 32;
  constexpr int BN = TN / 32;
  constexpr int AU = TM / 8;
  constexpr int TU = (TM + TN) / 8;
  constexpr int UPW = TU / 4;
  constexpr int NK = K / 32;

  __shared__ __align__(16) _Float16 s[2][(TM + TN) * 64];

  const int tid = threadIdx.x;
  const int lane = tid & 63;
  const int w = tid >> 6;
  const int wm = w >> 1, wn = w & 1;
  const int m0 = blockIdx.y * TM;
  const int n0 = blockIdx.x * TN;

  const int srow = lane >> 2;
  const int sk8 = (((lane & 3) - (lane >> 3)) & 3) * 8;

  const _Float16* gb[UPW];
  int lo[UPW];
#pragma unroll
  for (int i = 0; i < UPW; ++i) {
    const int u = w * UPW + i;
    if (u < AU) {
      const int g = u >> 1, hl = u & 1;
      gb[i] = (hl ? Al : Ah) + (size_t)(m0 + g * 16 + srow) * K + sk8;
    } else {
      const int ub = u - AU;
      const int g = ub >> 1, hl = ub & 1;
      gb[i] = (hl ? Bl : Bh) + (size_t)(n0 + g * 16 + srow) * K + sk8;
    }
    lo[i] = u * 512;
  }

  const int fr = lane & 15;
  const int fq = lane >> 4;
  const int fslot8 = (4 * fr + ((fq + (fr >> 1)) & 3)) * 8;

  f32x4 acc1[AM][BN], acc2[AM][BN];
#pragma unroll
  for (int i = 0; i < AM; i++)
#pragma unroll
    for (int j = 0; j < BN; j++) {
      acc1[i][j] = 0.0f;
      acc2[i][j] = 0.0f;
    }

#pragma unroll
  for (int i = 0; i < UPW; ++i) load16_lds(gb[i], &s[0][lo[i]]);

  for (int kt = 0; kt < NK; ++kt) {
    const int cur = kt & 1;
    __syncthreads();

    if (kt + 1 < NK) {
      const int kofs = (kt + 1) * 32;
#pragma unroll
      for (int i = 0; i < UPW; ++i) load16_lds(gb[i] + kofs, &s[cur ^ 1][lo[i]]);
    }

    f16x8 fAh[AM], fAl[AM], fBh[BN], fBl[BN];
#pragma unroll
    for (int im = 0; im < AM; ++im) {
      const int g = wm * AM + im;
      fAh[im] = *(const f16x8*)(&s[cur][(g * 2 + 0) * 512 + fslot8]);
      fAl[im] = *(const f16x8*)(&s[cur][(g * 2 + 1) * 512 + fslot8]);
    }
#pragma unroll
    for (int in = 0; in < BN; ++in) {
      const int g = wn * BN + in;
      fBh[in] = *(const f16x8*)(&s[cur][TM * 64 + (g * 2 + 0) * 512 + fslot8]);
      fBl[in] = *(const f16x8*)(&s[cur][TM * 64 + (g * 2 + 1) * 512 + fslot8]);
    }
#pragma unroll
    for (int im = 0; im < AM; ++im) {
#pragma unroll
      for (int in = 0; in < BN; ++in) {
        acc1[im][in] = __builtin_amdgcn_mfma_f32_16x16x32_f16(fAh[im], fBh[in], acc1[im][in], 0, 0, 0);
        acc2[im][in] = __builtin_amdgcn_mfma_f32_16x16x32_f16(fAh[im], fBl[in], acc2[im][in], 0, 0, 0);
        acc2[im][in] = __builtin_amdgcn_mfma_f32_16x16x32_f16(fAl[im], fBh[in], acc2[im][in], 0, 0, 0);
      }
    }
  }

  const int quad = lane >> 4;
#pragma unroll
  for (int in = 0; in < BN; ++in) {
    const int n = n0 + wn * (TN / 2) + in * 16 + fr;
    const float bv = bias[n];
#pragma unroll
    for (int im = 0; im < AM; ++im) {
#pragma unroll
      for (int r = 0; r < 4; ++r) {
        const int m = m0 + wm * (TM / 2) + im * 16 + quad * 4 + r;
        float c = (acc1[im][in][r] + acc2[im][in][r] * (1.0f / 4096.0f)) * (1.0f / 256.0f) + bv;
        if (RELU) c = fmaxf(c, 0.0f);
        const size_t off = (size_t)m * N + n;
        if (SPLIT_OUT) {
          HL rr = split_one(c);
          Ch[off] = rr.h;
          Cl[off] = rr.l;
        } else {
          Cf[off] = c;
        }
      }
    }
  }
}

// ---------------------------------------------------------------------------
// G1 split-K GEMM, B direct-from-global (no LDS for B).
// Wave grid 1x4: wave w owns all TM rows x cols [w*TN/4, (w+1)*TN/4).
// A staged via global_load_lds (double-buffered, verified swizzle); B frag for
// 16x16x32 is lane (fr,fq) <- B[col=fr][k=fq*8..+8] = per-lane global dwordx4.
// Per K-step: barrier -> B loads (kt) -> A staging (kt+1) -> A ds_reads -> MFMAs.
// B issued before staging so the compiler's B-wait is vmcnt(4); staging stays
// in flight across the MFMA block.
// ---------------------------------------------------------------------------
template <int TM, int TN, int N, int K, int KSPLIT>
__global__ void __launch_bounds__(256, 1)
gemm_g1(const _Float16* __restrict__ Ah, const _Float16* __restrict__ Al,
        const _Float16* __restrict__ Bh, const _Float16* __restrict__ Bl,
        float* __restrict__ Cp) {
  constexpr int AM = TM / 16;          // 8 A frag-rows (wave covers all rows)
  constexpr int BN = TN / 4 / 16;      // 4 B frag-cols per wave
  constexpr int AU = TM / 8;           // 16 A staging units (row-group x hi/lo)
  constexpr int UPW = AU / 4;          // 4 staging units per wave
  constexpr int NK = K / KSPLIT / 32;

  __shared__ __align__(16) _Float16 s[2][AU * 512];  // 32 KB, A only

  const int tid = threadIdx.x;
  const int lane = tid & 63;
  const int w = tid >> 6;
  const int m0 = blockIdx.y * TM;
  const int n0 = blockIdx.x * TN;
  const int kb = blockIdx.z * (K / KSPLIT);

  // A staging swizzle (R4-verified)
  const int srow = lane >> 2;
  const int sk8 = (((lane & 3) - (lane >> 3)) & 3) * 8;

  const _Float16* gb[UPW];
  int lo[UPW];
#pragma unroll
  for (int i = 0; i < UPW; ++i) {
    const int u = w * UPW + i;
    const int g = u >> 1, hl = u & 1;
    gb[i] = (hl ? Al : Ah) + (size_t)(m0 + g * 16 + srow) * K + kb + sk8;
    lo[i] = u * 512;
  }

  // fragment-read swizzled lane offset (R4-verified)
  const int fr = lane & 15;
  const int fq = lane >> 4;
  const int fslot8 = (4 * fr + ((fq + (fr >> 1)) & 3)) * 8;

  // B direct per-lane base: col = n0 + w*(TN/4) + fr (+ in*16), k = kb + fq*8 (+ kt*32)
  const _Float16* Bhb = Bh + (size_t)(n0 + w * (TN / 4) + fr) * K + kb + fq * 8;
  const _Float16* Blb = Bl + (size_t)(n0 + w * (TN / 4) + fr) * K + kb + fq * 8;

  f32x4 acc1[AM][BN], acc2[AM][BN];
#pragma unroll
  for (int i = 0; i < AM; i++)
#pragma unroll
    for (int j = 0; j < BN; j++) {
      acc1[i][j] = 0.0f;
      acc2[i][j] = 0.0f;
    }

  // prologue: stage A k=0 into buffer 0
#pragma unroll
  for (int i = 0; i < UPW; ++i) load16_lds(gb[i], &s[0][lo[i]]);

  for (int kt = 0; kt < NK; ++kt) {
    const int cur = kt & 1;
    __syncthreads();  // drains stage(kt); protects buf(cur^1) reads from last iter

    // B loads for this step (before staging so B-wait leaves staging in flight)
    f16x8 fBh[BN], fBl[BN];
#pragma unroll
    for (int in = 0; in < BN; ++in) {
      const size_t bo = (size_t)in * 16 * K + kt * 32;
      fBh[in] = *(const f16x8*)(Bhb + bo);
      fBl[in] = *(const f16x8*)(Blb + bo);
    }

    if (kt + 1 < NK) {
      const int kofs = (kt + 1) * 32;
#pragma unroll
      for (int i = 0; i < UPW; ++i) load16_lds(gb[i] + kofs, &s[cur ^ 1][lo[i]]);
    }

    f16x8 fAh[AM], fAl[AM];
#pragma unroll
    for (int im = 0; im < AM; ++im) {
      fAh[im] = *(const f16x8*)(&s[cur][(im * 2 + 0) * 512 + fslot8]);
      fAl[im] = *(const f16x8*)(&s[cur][(im * 2 + 1) * 512 + fslot8]);
    }
#pragma unroll
    for (int im = 0; im < AM; ++im) {
#pragma unroll
      for (int in = 0; in < BN; ++in) {
        acc1[im][in] = __builtin_amdgcn_mfma_f32_16x16x32_f16(fAh[im], fBh[in], acc1[im][in], 0, 0, 0);
        acc2[im][in] = __builtin_amdgcn_mfma_f32_16x16x32_f16(fAh[im], fBl[in], acc2[im][in], 0, 0, 0);
        acc2[im][in] = __builtin_amdgcn_mfma_f32_16x16x32_f16(fAl[im], fBh[in], acc2[im][in], 0, 0, 0);
      }
    }
  }

  // epilogue: raw f32 partial. C/D layout col=lane&15, row=quad*4+reg
  const int quad = lane >> 4;
  float* Cz = Cp + (size_t)blockIdx.z * ((size_t)gridDim.y * TM) * N;
#pragma unroll
  for (int in = 0; in < BN; ++in) {
    const int n = n0 + w * (TN / 4) + in * 16 + fr;
#pragma unroll
    for (int im = 0; im < AM; ++im) {
#pragma unroll
      for (int r = 0; r < 4; ++r) {
        const int m = m0 + im * 16 + quad * 4 + r;
        Cz[(size_t)m * N + n] = acc1[im][in][r] + acc2[im][in][r] * (1.0f / 4096.0f);
      }
    }
  }
}

// ---------------------------------------------------------------------------
// combine: c = (p0 + p1) * (1/256) + bias[n]; relu; split f16 out. (R8-verified)
// ---------------------------------------------------------------------------
__global__ void __launch_bounds__(256)
combine1(const float* __restrict__ Cp, const float* __restrict__ bias, int N,
         size_t halfN, _Float16* __restrict__ Ch, _Float16* __restrict__ Cl) {
  const size_t i4 = ((size_t)blockIdx.x * 256 + threadIdx.x) * 4;
  float4 p0 = *(const float4*)(Cp + i4);
  float4 p1 = *(const float4*)(Cp + halfN + i4);
  float4 bv = *(const float4*)(bias + (i4 % (size_t)N));
  float c[4] = {(p0.x + p1.x) * (1.0f / 256.0f) + bv.x,
                (p0.y + p1.y) * (1.0f / 256.0f) + bv.y,
                (p0.z + p1.z) * (1.0f / 256.0f) + bv.z,
                (p0.w + p1.w) * (1.0f / 256.0f) + bv.w};
  f16x4 h, l;
#pragma unroll
  for (int j = 0; j < 4; j++) {
    c[j] = fmaxf(c[j], 0.0f);
    HL r = split_one(c[j]);
    h[j] = r.h;
    l[j] = r.l;
  }
  *(f16x4*)(Ch + i4) = h;
  *(f16x4*)(Cl + i4) = l;
}

// ---------------------------------------------------------------------------
// Gabor synthesis: one block per batch; thread owns 8 contiguous t samples,
// per-wavelet wave-uniform 5-sigma window skip.
// ---------------------------------------------------------------------------
__global__ void __launch_bounds__(256)
synth(const float* __restrict__ P, float* __restrict__ out) {
  __shared__ float sA[NWAV], sT0[NWAV], sF[NWAV], sC[NWAV], sPh[NWAV], sSg[NWAV];
  const int b = blockIdx.x;
  const int tid = threadIdx.x;
  if (tid < NWAV) {
    const float* q = P + (size_t)b * 256 + tid * 5;
    const float L2E = 1.44269504088896340736f;
    float A = q[0], p1 = q[1], p2 = q[2], p3 = q[3], p4 = q[4];
    float s1 = 1.0f / (1.0f + exp2f(-p1 * L2E));
    float s2 = 1.0f / (1.0f + exp2f(-p2 * L2E));
    float s3 = 1.0f / (1.0f + exp2f(-p3 * L2E));
    float sg = s3 * 200.0f + 2.0f;
    sA[tid] = A;
    sT0[tid] = s1 * 2048.0f;
    sF[tid] = s2 * 0.5f;
    sC[tid] = -L2E / (2.0f * sg * sg);
    sPh[tid] = p4 * 0.15915494309189535f;
    sSg[tid] = sg;
  }
  __syncthreads();

  const float t0f = (float)(tid * 8);
  const int wlo = (tid & ~63) * 8;
  float acc[8];
#pragma unroll
  for (int i = 0; i < 8; i++) acc[i] = 0.0f;

  for (int wv = 0; wv < NWAV; wv++) {
    const float t0 = sT0[wv], sg = sSg[wv];
    if (t0 + 5.0f * sg < (float)wlo || t0 - 5.0f * sg > (float)(wlo + 511)) continue;
    const float A = sA[wv], fr = sF[wv], cn = sC[wv], ph = sPh[wv];
#pragma unroll
    for (int i = 0; i < 8; i++) {
      float dt = (t0f + (float)i) - t0;
      float e = exp2f(dt * dt * cn);
      float r = fr * dt + ph;
      r -= floorf(r);
      float cs = __builtin_amdgcn_cosf(r);
      acc[i] += A * e * cs;
    }
  }

  float* o = out + (size_t)b * (2 * SIGNAL_LEN) + tid * 8;
  float4 v0 = make_float4(acc[0], acc[1], acc[2], acc[3]);
  float4 v1 = make_float4(acc[4], acc[5], acc[6], acc[7]);
  *(float4*)(o) = v0;
  *(float4*)(o + 4) = v1;
  *(float4*)(o + SIGNAL_LEN) = v0;
  *(float4*)(o + SIGNAL_LEN + 4) = v1;
}

// ---------------------------------------------------------------------------
extern "C" void kernel_launch(void* const* d_in, const int* in_sizes, int n_in,
                              void* d_out, int out_size, void* d_ws, size_t ws_size,
                              hipStream_t stream) {
  (void)in_sizes; (void)n_in; (void)out_size; (void)ws_size;
  const float* X  = (const float*)d_in[0];
  const float* W1 = (const float*)d_in[1];
  const float* b1 = (const float*)d_in[2];
  const float* W2 = (const float*)d_in[3];
  const float* b2 = (const float*)d_in[4];
  const float* W3 = (const float*)d_in[5];
  const float* b3 = (const float*)d_in[6];
  const float* W4 = (const float*)d_in[7];
  const float* b4 = (const float*)d_in[8];
  float* out = (float*)d_out;

  char* p = (char*)d_ws;
  auto take = [&](size_t bytes) -> char* {
    char* r = p;
    p += (bytes + 255) & ~(size_t)255;
    return r;
  };
  _Float16* Xh  = (_Float16*)take((size_t)4096 * 4096 * 2);
  _Float16* Xl  = (_Float16*)take((size_t)4096 * 4096 * 2);
  _Float16* W1h = (_Float16*)take((size_t)1024 * 4096 * 2);
  _Float16* W1l = (_Float16*)take((size_t)1024 * 4096 * 2);
  _Float16* H1h = (_Float16*)take((size_t)4096 * 1024 * 2);
  _Float16* H1l = (_Float16*)take((size_t)4096 * 1024 * 2);
  _Float16* W2h = (_Float16*)take((size_t)512 * 1024 * 2);
  _Float16* W2l = (_Float16*)take((size_t)512 * 1024 * 2);
  _Float16* H2h = (_Float16*)take((size_t)4096 * 512 * 2);
  _Float16* H2l = (_Float16*)take((size_t)4096 * 512 * 2);
  _Float16* W3h = (_Float16*)take((size_t)256 * 512 * 2);
  _Float16* W3l = (_Float16*)take((size_t)256 * 512 * 2);
  _Float16* H3h = (_Float16*)take((size_t)4096 * 256 * 2);
  _Float16* H3l = (_Float16*)take((size_t)4096 * 256 * 2);
  _Float16* W4h = (_Float16*)take((size_t)256 * 256 * 2);
  _Float16* W4l = (_Float16*)take((size_t)256 * 256 * 2);
  float*    b4p = (float*)take(256 * 4);
  float*    Pp  = (float*)take((size_t)4096 * 256 * 4);
  float*    Cp  = (float*)take((size_t)2 * 4096 * 1024 * 4);  // G1 split-K partials

  split_x<<<16384, 256, 0, stream>>>((const float4*)X, (f16x4*)Xh, (f16x4*)Xl);
  split_weights<<<4801, 256, 0, stream>>>(W1, W2, W3, W4, b4,
                                          (f16x4*)W1h, (f16x4*)W1l, (f16x4*)W2h, (f16x4*)W2l,
                                          (f16x4*)W3h, (f16x4*)W3l, (f16x4*)W4h, (f16x4*)W4l, b4p);

  // G1: 128x256 tile, 1x4 wave grid, B direct, splitK=2 -> 256 blocks, LDS 32KB
  gemm_g1<128, 256, 1024, 4096, 2><<<dim3(4, 32, 2), 256, 0, stream>>>(
      Xh, Xl, W1h, W1l, Cp);
  combine1<<<4096, 256, 0, stream>>>(Cp, b1, 1024, (size_t)4096 * 1024, H1h, H1l);

  // G2-4: R5-exact fused kernels
  gemm_fused<64, 128, 512, 1024, true, true><<<dim3(4, 64), 256, 0, stream>>>(
      H1h, H1l, W2h, W2l, b2, H2h, H2l, nullptr);
  gemm_fused<64, 64, 256, 512, true, true><<<dim3(4, 64), 256, 0, stream>>>(
      H2h, H2l, W3h, W3l, b3, H3h, H3l, nullptr);
  gemm_fused<64, 64, 256, 256, false, false><<<dim3(4, 64), 256, 0, stream>>>(
      H3h, H3l, W4h, W4l, b4p, nullptr, nullptr, Pp);

  synth<<<4096, 256, 0, stream>>>(Pp, out);
}

// Round 6
// 395.546 us; speedup vs baseline: 1.1452x; 1.1452x over previous
//
#include <hip/hip_runtime.h>

// GaborAutoencoder on MI355X (gfx950)
// split fp32 -> fp16 (hi, lo*4096) -> 3-pass split-precision MFMA GEMMs -> Gabor synth.
// R11: G1 reverted to R9-exact (best measured 120.7us; R10's B-direct had zero
//      prefetch depth on B -> per-step latency stall, 178us).
//      G2-4 re-tiled for 2 blocks/CU (they ran 256 blocks = 1/CU, latency-serial
//      like G1 was): G2 64x64 grid (8,64); G3/G4 32x64 grid (4,128) = 512 blocks.
//      LDS 32/24/24 KB per block, VGPR 108 < 128 cap -> 2 blocks resident; the
//      second block fills each barrier drain (R8 mechanism, stronger here since
//      small-tile steps are latency-dominated).
//      R4-verified swizzles kept everywhere.

#define SIGNAL_LEN 2048
#define NWAV 32

typedef _Float16 f16x8 __attribute__((ext_vector_type(8)));
typedef _Float16 f16x4 __attribute__((ext_vector_type(4)));
typedef float    f32x4 __attribute__((ext_vector_type(4)));

__device__ __forceinline__ void load16_lds(const _Float16* g, _Float16* l) {
  __builtin_amdgcn_global_load_lds((const __attribute__((address_space(1))) void*)g,
                                   (__attribute__((address_space(3))) void*)l,
                                   16, 0, 0);
}

struct HL { _Float16 h, l; };
__device__ __forceinline__ HL split_one(float a) {
  HL r;
  r.h = (_Float16)a;
  r.l = (_Float16)((a - (float)r.h) * 4096.0f);
  return r;
}

// ---------------------------------------------------------------------------
// X split: fp32 float4 -> hi/lo f16x4
// ---------------------------------------------------------------------------
__global__ void split_x(const float4* __restrict__ src, f16x4* __restrict__ dh,
                        f16x4* __restrict__ dl) {
  int i = blockIdx.x * 256 + threadIdx.x;  // 4194304 float4s
  float4 v = src[i];
  float a[4] = {v.x, v.y, v.z, v.w};
  f16x4 h, l;
#pragma unroll
  for (int j = 0; j < 4; j++) {
    HL r = split_one(a[j]);
    h[j] = r.h;
    l[j] = r.l;
  }
  dh[i] = h;
  dl[i] = l;
}

// ---------------------------------------------------------------------------
// all weight splits in one launch (scaled x256); W4 padded 160x256 -> 256x256
// ---------------------------------------------------------------------------
__global__ void split_weights(const float* __restrict__ W1, const float* __restrict__ W2,
                              const float* __restrict__ W3, const float* __restrict__ W4,
                              const float* __restrict__ b4,
                              f16x4* __restrict__ W1h, f16x4* __restrict__ W1l,
                              f16x4* __restrict__ W2h, f16x4* __restrict__ W2l,
                              f16x4* __restrict__ W3h, f16x4* __restrict__ W3l,
                              f16x4* __restrict__ W4h, f16x4* __restrict__ W4l,
                              float* __restrict__ b4p) {
  const int blk = blockIdx.x;
  const int tid = threadIdx.x;
  if (blk < 4736) {
    const float4* src;
    f16x4 *dh, *dl;
    int i;
    if (blk < 4096) {
      src = (const float4*)W1; dh = W1h; dl = W1l; i = blk * 256 + tid;
    } else if (blk < 4608) {
      src = (const float4*)W2; dh = W2h; dl = W2l; i = (blk - 4096) * 256 + tid;
    } else {
      src = (const float4*)W3; dh = W3h; dl = W3l; i = (blk - 4608) * 256 + tid;
    }
    float4 v = src[i];
    float a[4] = {v.x * 256.0f, v.y * 256.0f, v.z * 256.0f, v.w * 256.0f};
    f16x4 h, l;
#pragma unroll
    for (int j = 0; j < 4; j++) {
      HL r = split_one(a[j]);
      h[j] = r.h;
      l[j] = r.l;
    }
    dh[i] = h;
    dl[i] = l;
  } else if (blk < 4800) {
    int i = (blk - 4736) * 256 + tid;
    int i4 = i << 2;
    int row = i4 >> 8;
    f16x4 h, l;
#pragma unroll
    for (int j = 0; j < 4; j++) {
      float a = (row < 160) ? W4[i4 + j] * 256.0f : 0.0f;
      HL r = split_one(a);
      h[j] = r.h;
      l[j] = r.l;
    }
    W4h[i] = h;
    W4l[i] = l;
  } else {
    b4p[tid] = (tid < 160) ? b4[tid] : 0.0f;
  }
}

// ---------------------------------------------------------------------------
// R5 fused GEMM (G2-4): fp16x2 split-precision, double-buffered, fused epilogue.
// C[M,N] = A[M,K]*B[N,K]^T (+bias, relu). Tile TM x TN, 256 threads = 4 waves
// (2x2), wave tile (TM/2)x(TN/2) of 16x16x32 MFMAs. One barrier per K32 step.
// ---------------------------------------------------------------------------
template <int TM, int TN, int N, int K, bool RELU, bool SPLIT_OUT>
__global__ void __launch_bounds__(256, 2)
gemm_fused(const _Float16* __restrict__ Ah, const _Float16* __restrict__ Al,
           const _Float16* __restrict__ Bh, const _Float16* __restrict__ Bl,
           const float* __restrict__ bias,
           _Float16* __restrict__ Ch, _Float16* __restrict__ Cl,
           float* __restrict__ Cf) {
  constexpr int AM = TM / 32;
  constexpr int BN = TN / 32;
  constexpr int AU = TM / 8;
  constexpr int TU = (TM + TN) / 8;
  constexpr int UPW = TU / 4;
  constexpr int NK = K / 32;

  __shared__ __align__(16) _Float16 s[2][(TM + TN) * 64];

  const int tid = threadIdx.x;
  const int lane = tid & 63;
  const int w = tid >> 6;
  const int wm = w >> 1, wn = w & 1;
  const int m0 = blockIdx.y * TM;
  const int n0 = blockIdx.x * TN;

  const int srow = lane >> 2;
  const int sk8 = (((lane & 3) - (lane >> 3)) & 3) * 8;

  const _Float16* gb[UPW];
  int lo[UPW];
#pragma unroll
  for (int i = 0; i < UPW; ++i) {
    const int u = w * UPW + i;
    if (u < AU) {
      const int g = u >> 1, hl = u & 1;
      gb[i] = (hl ? Al : Ah) + (size_t)(m0 + g * 16 + srow) * K + sk8;
    } else {
      const int ub = u - AU;
      const int g = ub >> 1, hl = ub & 1;
      gb[i] = (hl ? Bl : Bh) + (size_t)(n0 + g * 16 + srow) * K + sk8;
    }
    lo[i] = u * 512;
  }

  const int fr = lane & 15;
  const int fq = lane >> 4;
  const int fslot8 = (4 * fr + ((fq + (fr >> 1)) & 3)) * 8;

  f32x4 acc1[AM][BN], acc2[AM][BN];
#pragma unroll
  for (int i = 0; i < AM; i++)
#pragma unroll
    for (int j = 0; j < BN; j++) {
      acc1[i][j] = 0.0f;
      acc2[i][j] = 0.0f;
    }

#pragma unroll
  for (int i = 0; i < UPW; ++i) load16_lds(gb[i], &s[0][lo[i]]);

  for (int kt = 0; kt < NK; ++kt) {
    const int cur = kt & 1;
    __syncthreads();

    if (kt + 1 < NK) {
      const int kofs = (kt + 1) * 32;
#pragma unroll
      for (int i = 0; i < UPW; ++i) load16_lds(gb[i] + kofs, &s[cur ^ 1][lo[i]]);
    }

    f16x8 fAh[AM], fAl[AM], fBh[BN], fBl[BN];
#pragma unroll
    for (int im = 0; im < AM; ++im) {
      const int g = wm * AM + im;
      fAh[im] = *(const f16x8*)(&s[cur][(g * 2 + 0) * 512 + fslot8]);
      fAl[im] = *(const f16x8*)(&s[cur][(g * 2 + 1) * 512 + fslot8]);
    }
#pragma unroll
    for (int in = 0; in < BN; ++in) {
      const int g = wn * BN + in;
      fBh[in] = *(const f16x8*)(&s[cur][TM * 64 + (g * 2 + 0) * 512 + fslot8]);
      fBl[in] = *(const f16x8*)(&s[cur][TM * 64 + (g * 2 + 1) * 512 + fslot8]);
    }
#pragma unroll
    for (int im = 0; im < AM; ++im) {
#pragma unroll
      for (int in = 0; in < BN; ++in) {
        acc1[im][in] = __builtin_amdgcn_mfma_f32_16x16x32_f16(fAh[im], fBh[in], acc1[im][in], 0, 0, 0);
        acc2[im][in] = __builtin_amdgcn_mfma_f32_16x16x32_f16(fAh[im], fBl[in], acc2[im][in], 0, 0, 0);
        acc2[im][in] = __builtin_amdgcn_mfma_f32_16x16x32_f16(fAl[im], fBh[in], acc2[im][in], 0, 0, 0);
      }
    }
  }

  const int quad = lane >> 4;
#pragma unroll
  for (int in = 0; in < BN; ++in) {
    const int n = n0 + wn * (TN / 2) + in * 16 + fr;
    const float bv = bias[n];
#pragma unroll
    for (int im = 0; im < AM; ++im) {
#pragma unroll
      for (int r = 0; r < 4; ++r) {
        const int m = m0 + wm * (TM / 2) + im * 16 + quad * 4 + r;
        float c = (acc1[im][in][r] + acc2[im][in][r] * (1.0f / 4096.0f)) * (1.0f / 256.0f) + bv;
        if (RELU) c = fmaxf(c, 0.0f);
        const size_t off = (size_t)m * N + n;
        if (SPLIT_OUT) {
          HL rr = split_one(c);
          Ch[off] = rr.h;
          Cl[off] = rr.l;
        } else {
          Cf[off] = c;
        }
      }
    }
  }
}

// ---------------------------------------------------------------------------
// G1 split-K partial GEMM (R9-exact): verified structure, raw f32 partial out.
// ---------------------------------------------------------------------------
template <int TM, int TN, int N, int K, int KSPLIT, int MINW>
__global__ void __launch_bounds__(256, MINW)
gemm_part(const _Float16* __restrict__ Ah, const _Float16* __restrict__ Al,
          const _Float16* __restrict__ Bh, const _Float16* __restrict__ Bl,
          float* __restrict__ Cp) {
  constexpr int AM = TM / 32;
  constexpr int BN = TN / 32;
  constexpr int AU = TM / 8;
  constexpr int TU = (TM + TN) / 8;
  constexpr int UPW = TU / 4;
  constexpr int NK = K / KSPLIT / 32;

  __shared__ __align__(16) _Float16 s[2][(TM + TN) * 64];

  const int tid = threadIdx.x;
  const int lane = tid & 63;
  const int w = tid >> 6;
  const int wm = w >> 1, wn = w & 1;
  const int m0 = blockIdx.y * TM;
  const int n0 = blockIdx.x * TN;
  const int kb = blockIdx.z * (K / KSPLIT);

  const int srow = lane >> 2;
  const int sk8 = (((lane & 3) - (lane >> 3)) & 3) * 8;

  const _Float16* gb[UPW];
  int lo[UPW];
#pragma unroll
  for (int i = 0; i < UPW; ++i) {
    const int u = w * UPW + i;
    if (u < AU) {
      const int g = u >> 1, hl = u & 1;
      gb[i] = (hl ? Al : Ah) + (size_t)(m0 + g * 16 + srow) * K + kb + sk8;
    } else {
      const int ub = u - AU;
      const int g = ub >> 1, hl = ub & 1;
      gb[i] = (hl ? Bl : Bh) + (size_t)(n0 + g * 16 + srow) * K + kb + sk8;
    }
    lo[i] = u * 512;
  }

  const int fr = lane & 15;
  const int fq = lane >> 4;
  const int fslot8 = (4 * fr + ((fq + (fr >> 1)) & 3)) * 8;

  f32x4 acc1[AM][BN], acc2[AM][BN];
#pragma unroll
  for (int i = 0; i < AM; i++)
#pragma unroll
    for (int j = 0; j < BN; j++) {
      acc1[i][j] = 0.0f;
      acc2[i][j] = 0.0f;
    }

#pragma unroll
  for (int i = 0; i < UPW; ++i) load16_lds(gb[i], &s[0][lo[i]]);

  for (int kt = 0; kt < NK; ++kt) {
    const int cur = kt & 1;
    __syncthreads();

    if (kt + 1 < NK) {
      const int kofs = (kt + 1) * 32;
#pragma unroll
      for (int i = 0; i < UPW; ++i) load16_lds(gb[i] + kofs, &s[cur ^ 1][lo[i]]);
    }

    f16x8 fAh[AM], fAl[AM], fBh[BN], fBl[BN];
#pragma unroll
    for (int im = 0; im < AM; ++im) {
      const int g = wm * AM + im;
      fAh[im] = *(const f16x8*)(&s[cur][(g * 2 + 0) * 512 + fslot8]);
      fAl[im] = *(const f16x8*)(&s[cur][(g * 2 + 1) * 512 + fslot8]);
    }
#pragma unroll
    for (int in = 0; in < BN; ++in) {
      const int g = wn * BN + in;
      fBh[in] = *(const f16x8*)(&s[cur][TM * 64 + (g * 2 + 0) * 512 + fslot8]);
      fBl[in] = *(const f16x8*)(&s[cur][TM * 64 + (g * 2 + 1) * 512 + fslot8]);
    }
#pragma unroll
    for (int im = 0; im < AM; ++im) {
#pragma unroll
      for (int in = 0; in < BN; ++in) {
        acc1[im][in] = __builtin_amdgcn_mfma_f32_16x16x32_f16(fAh[im], fBh[in], acc1[im][in], 0, 0, 0);
        acc2[im][in] = __builtin_amdgcn_mfma_f32_16x16x32_f16(fAh[im], fBl[in], acc2[im][in], 0, 0, 0);
        acc2[im][in] = __builtin_amdgcn_mfma_f32_16x16x32_f16(fAl[im], fBh[in], acc2[im][in], 0, 0, 0);
      }
    }
  }

  const int quad = lane >> 4;
  float* Cz = Cp + (size_t)blockIdx.z * ((size_t)gridDim.y * TM) * N;
#pragma unroll
  for (int in = 0; in < BN; ++in) {
    const int n = n0 + wn * (TN / 2) + in * 16 + fr;
#pragma unroll
    for (int im = 0; im < AM; ++im) {
#pragma unroll
      for (int r = 0; r < 4; ++r) {
        const int m = m0 + wm * (TM / 2) + im * 16 + quad * 4 + r;
        Cz[(size_t)m * N + n] = acc1[im][in][r] + acc2[im][in][r] * (1.0f / 4096.0f);
      }
    }
  }
}

// ---------------------------------------------------------------------------
// combine: c = (p0 + p1) * (1/256) + bias[n]; relu; split f16 out. (R8-verified)
// ---------------------------------------------------------------------------
__global__ void __launch_bounds__(256)
combine1(const float* __restrict__ Cp, const float* __restrict__ bias, int N,
         size_t halfN, _Float16* __restrict__ Ch, _Float16* __restrict__ Cl) {
  const size_t i4 = ((size_t)blockIdx.x * 256 + threadIdx.x) * 4;
  float4 p0 = *(const float4*)(Cp + i4);
  float4 p1 = *(const float4*)(Cp + halfN + i4);
  float4 bv = *(const float4*)(bias + (i4 % (size_t)N));
  float c[4] = {(p0.x + p1.x) * (1.0f / 256.0f) + bv.x,
                (p0.y + p1.y) * (1.0f / 256.0f) + bv.y,
                (p0.z + p1.z) * (1.0f / 256.0f) + bv.z,
                (p0.w + p1.w) * (1.0f / 256.0f) + bv.w};
  f16x4 h, l;
#pragma unroll
  for (int j = 0; j < 4; j++) {
    c[j] = fmaxf(c[j], 0.0f);
    HL r = split_one(c[j]);
    h[j] = r.h;
    l[j] = r.l;
  }
  *(f16x4*)(Ch + i4) = h;
  *(f16x4*)(Cl + i4) = l;
}

// ---------------------------------------------------------------------------
// Gabor synthesis: one block per batch; thread owns 8 contiguous t samples,
// per-wavelet wave-uniform 5-sigma window skip.
// ---------------------------------------------------------------------------
__global__ void __launch_bounds__(256)
synth(const float* __restrict__ P, float* __restrict__ out) {
  __shared__ float sA[NWAV], sT0[NWAV], sF[NWAV], sC[NWAV], sPh[NWAV], sSg[NWAV];
  const int b = blockIdx.x;
  const int tid = threadIdx.x;
  if (tid < NWAV) {
    const float* q = P + (size_t)b * 256 + tid * 5;
    const float L2E = 1.44269504088896340736f;
    float A = q[0], p1 = q[1], p2 = q[2], p3 = q[3], p4 = q[4];
    float s1 = 1.0f / (1.0f + exp2f(-p1 * L2E));
    float s2 = 1.0f / (1.0f + exp2f(-p2 * L2E));
    float s3 = 1.0f / (1.0f + exp2f(-p3 * L2E));
    float sg = s3 * 200.0f + 2.0f;
    sA[tid] = A;
    sT0[tid] = s1 * 2048.0f;
    sF[tid] = s2 * 0.5f;
    sC[tid] = -L2E / (2.0f * sg * sg);
    sPh[tid] = p4 * 0.15915494309189535f;
    sSg[tid] = sg;
  }
  __syncthreads();

  const float t0f = (float)(tid * 8);
  const int wlo = (tid & ~63) * 8;
  float acc[8];
#pragma unroll
  for (int i = 0; i < 8; i++) acc[i] = 0.0f;

  for (int wv = 0; wv < NWAV; wv++) {
    const float t0 = sT0[wv], sg = sSg[wv];
    if (t0 + 5.0f * sg < (float)wlo || t0 - 5.0f * sg > (float)(wlo + 511)) continue;
    const float A = sA[wv], fr = sF[wv], cn = sC[wv], ph = sPh[wv];
#pragma unroll
    for (int i = 0; i < 8; i++) {
      float dt = (t0f + (float)i) - t0;
      float e = exp2f(dt * dt * cn);
      float r = fr * dt + ph;
      r -= floorf(r);
      float cs = __builtin_amdgcn_cosf(r);
      acc[i] += A * e * cs;
    }
  }

  float* o = out + (size_t)b * (2 * SIGNAL_LEN) + tid * 8;
  float4 v0 = make_float4(acc[0], acc[1], acc[2], acc[3]);
  float4 v1 = make_float4(acc[4], acc[5], acc[6], acc[7]);
  *(float4*)(o) = v0;
  *(float4*)(o + 4) = v1;
  *(float4*)(o + SIGNAL_LEN) = v0;
  *(float4*)(o + SIGNAL_LEN + 4) = v1;
}

// ---------------------------------------------------------------------------
extern "C" void kernel_launch(void* const* d_in, const int* in_sizes, int n_in,
                              void* d_out, int out_size, void* d_ws, size_t ws_size,
                              hipStream_t stream) {
  (void)in_sizes; (void)n_in; (void)out_size; (void)ws_size;
  const float* X  = (const float*)d_in[0];
  const float* W1 = (const float*)d_in[1];
  const float* b1 = (const float*)d_in[2];
  const float* W2 = (const float*)d_in[3];
  const float* b2 = (const float*)d_in[4];
  const float* W3 = (const float*)d_in[5];
  const float* b3 = (const float*)d_in[6];
  const float* W4 = (const float*)d_in[7];
  const float* b4 = (const float*)d_in[8];
  float* out = (float*)d_out;

  char* p = (char*)d_ws;
  auto take = [&](size_t bytes) -> char* {
    char* r = p;
    p += (bytes + 255) & ~(size_t)255;
    return r;
  };
  _Float16* Xh  = (_Float16*)take((size_t)4096 * 4096 * 2);
  _Float16* Xl  = (_Float16*)take((size_t)4096 * 4096 * 2);
  _Float16* W1h = (_Float16*)take((size_t)1024 * 4096 * 2);
  _Float16* W1l = (_Float16*)take((size_t)1024 * 4096 * 2);
  _Float16* H1h = (_Float16*)take((size_t)4096 * 1024 * 2);
  _Float16* H1l = (_Float16*)take((size_t)4096 * 1024 * 2);
  _Float16* W2h = (_Float16*)take((size_t)512 * 1024 * 2);
  _Float16* W2l = (_Float16*)take((size_t)512 * 1024 * 2);
  _Float16* H2h = (_Float16*)take((size_t)4096 * 512 * 2);
  _Float16* H2l = (_Float16*)take((size_t)4096 * 512 * 2);
  _Float16* W3h = (_Float16*)take((size_t)256 * 512 * 2);
  _Float16* W3l = (_Float16*)take((size_t)256 * 512 * 2);
  _Float16* H3h = (_Float16*)take((size_t)4096 * 256 * 2);
  _Float16* H3l = (_Float16*)take((size_t)4096 * 256 * 2);
  _Float16* W4h = (_Float16*)take((size_t)256 * 256 * 2);
  _Float16* W4l = (_Float16*)take((size_t)256 * 256 * 2);
  float*    b4p = (float*)take(256 * 4);
  float*    Pp  = (float*)take((size_t)4096 * 256 * 4);
  float*    Cp  = (float*)take((size_t)2 * 4096 * 1024 * 4);  // G1 split-K partials

  split_x<<<16384, 256, 0, stream>>>((const float4*)X, (f16x4*)Xh, (f16x4*)Xl);
  split_weights<<<4801, 256, 0, stream>>>(W1, W2, W3, W4, b4,
                                          (f16x4*)W1h, (f16x4*)W1l, (f16x4*)W2h, (f16x4*)W2l,
                                          (f16x4*)W3h, (f16x4*)W3l, (f16x4*)W4h, (f16x4*)W4l, b4p);

  // G1: 128x256 tile, splitK=2 -> grid (4,32,2) = 256 blocks, LDS 96KB (R9-exact)
  gemm_part<128, 256, 1024, 4096, 2, 1><<<dim3(4, 32, 2), 256, 0, stream>>>(
      Xh, Xl, W1h, W1l, Cp);
  combine1<<<4096, 256, 0, stream>>>(Cp, b1, 1024, (size_t)4096 * 1024, H1h, H1l);

  // G2-4: fused kernels, halved tiles -> 512 blocks = 2 blocks/CU
  gemm_fused<64, 64, 512, 1024, true, true><<<dim3(8, 64), 256, 0, stream>>>(
      H1h, H1l, W2h, W2l, b2, H2h, H2l, nullptr);
  gemm_fused<32, 64, 256, 512, true, true><<<dim3(4, 128), 256, 0, stream>>>(
      H2h, H2l, W3h, W3l, b3, H3h, H3l, nullptr);
  gemm_fused<32, 64, 256, 256, false, false><<<dim3(4, 128), 256, 0, stream>>>(
      H3h, H3l, W4h, W4l, b4p, nullptr, nullptr, Pp);

  synth<<<4096, 256, 0, stream>>>(Pp, out);
}